// Round 15
// baseline (291.674 us; speedup 1.0000x reference)
//
#include <hip/hip_runtime.h>
#include <math.h>

#define T_IN          480000
#define OUT_PER_ROW   432000
#define PAIRS_PER_ROW 24000                 // k-pairs per row (2 groups of 9 outputs each)
#define TOT_PAIRS     (PAIRS_PER_ROW * 64)  // 1,536,000
#define BLK           256
#define NBLK          2048
#define NTH           (BLK * NBLK)          // 524,288 threads -> <=3 pairs/thread

typedef float f32x4 __attribute__((ext_vector_type(4)));
typedef float f32x2 __attribute__((ext_vector_type(2)));

struct ResampleW { float w[9][14]; };

__device__ __forceinline__ void load_window(const float* __restrict__ in,
                                            unsigned p, f32x4 r[9])
{
    const unsigned row = p / PAIRS_PER_ROW;          // magic-mul
    const int kp = (int)(p - row * PAIRS_PER_ROW);
    const float* rin = in + (size_t)row * T_IN;
    const int al = 20 * kp - 8;                      // 16B-aligned window base
    if (kp >= 1 && kp <= PAIRS_PER_ROW - 2) {        // interior: 9 independent dwordx4
        #pragma unroll
        for (int m = 0; m < 9; ++m)
            r[m] = *reinterpret_cast<const f32x4*>(rin + al + 4 * m);
    } else {                                          // 128 edge pairs total: scalar+bounds
        #pragma unroll
        for (int m = 0; m < 9; ++m) {
            #pragma unroll
            for (int c = 0; c < 4; ++c) {
                const int idx = al + 4 * m + c;
                r[m][c] = (idx >= 0 && idx < T_IN) ? rin[idx] : 0.f;
            }
        }
    }
}

__device__ __forceinline__ void compute_store(float* __restrict__ out,
                                              unsigned p, const f32x4 r[9],
                                              const ResampleW& args)
{
    const unsigned row = p / PAIRS_PER_ROW;
    const int kp = (int)(p - row * PAIRS_PER_ROW);
    float v[36];
    #pragma unroll
    for (int m = 0; m < 9; ++m) {
        v[4*m+0] = r[m][0]; v[4*m+1] = r[m][1];
        v[4*m+2] = r[m][2]; v[4*m+3] = r[m][3];
    }
    // RB[i] = fi[i] + 6, fi = ceil(i*10/9 - 6.7340067) = {-6..-1,0,2,3}
    constexpr int RB[9] = {0, 1, 2, 3, 4, 5, 6, 8, 9};
    float o[18];
    #pragma unroll
    for (int g = 0; g < 2; ++g) {
        #pragma unroll
        for (int i = 0; i < 9; ++i) {
            float s = 0.f;
            #pragma unroll
            for (int j = 0; j < 14; ++j)
                s = fmaf(args.w[i][j], v[2 + 10 * g + RB[i] + j], s);
            o[9 * g + i] = s;
        }
    }
    float* op = out + (size_t)row * OUT_PER_ROW + 18u * (size_t)kp;  // 8B-aligned
    #pragma unroll
    for (int m = 0; m < 9; ++m) {
        f32x2 t2; t2[0] = o[2*m]; t2[1] = o[2*m+1];
        __builtin_nontemporal_store(t2, reinterpret_cast<f32x2*>(op + 2 * m));
    }
}

__global__ __launch_bounds__(BLK)
void SpeedPerturb_resample_kernel(const float* __restrict__ in,
                                  float* __restrict__ out,
                                  ResampleW args)
{
    const unsigned tid = blockIdx.x * BLK + threadIdx.x;
    const unsigned p0 = tid;
    const unsigned p1 = tid + NTH;                  // always < TOT_PAIRS
    const unsigned p2 = tid + 2u * NTH;
    const bool has2 = p2 < TOT_PAIRS;

    f32x4 w0[9], w1[9], w2[9];
    // Stage 0+1 loads issued back-to-back: 18 dwordx4 in flight before any use.
    load_window(in, p0, w0);
    load_window(in, p1, w1);
    __builtin_amdgcn_sched_barrier(0);              // pin issue order: loads above compute

    compute_store(out, p0, w0, args);               // overlaps w1's in-flight loads
    if (has2) load_window(in, p2, w2);              // issue stage-2 loads before waiting on w1
    __builtin_amdgcn_sched_barrier(0);

    compute_store(out, p1, w1, args);               // overlaps w2's in-flight loads
    if (has2) compute_store(out, p2, w2, args);
}

extern "C" void kernel_launch(void* const* d_in, const int* in_sizes, int n_in,
                              void* d_out, int out_size, void* d_ws, size_t ws_size,
                              hipStream_t stream) {
    const float* in  = (const float*)d_in[0];
    float*       out = (float*)d_out;

    // Kaldi LinearResample weights, float64 math mirroring the reference.
    ResampleW args;
    const double orig = 16000.0;
    const double lowpass_cutoff = 0.99 * 0.5 * 14400.0;     // min_freq = 14400
    const double window_width = 6.0 / (2.0 * lowpass_cutoff);
    const double PI = 3.14159265358979323846;
    for (int i = 0; i < 9; ++i) {
        const double output_t = (double)i / 14400.0;
        const double min_input_index = ceil((output_t - window_width) * orig);
        for (int j = 0; j < 14; ++j) {
            const double delta_t = (min_input_index + j) / orig - output_t;
            double w = 0.0;
            if (fabs(delta_t) < window_width) {
                w = 0.5 * (1.0 + cos(2.0 * PI * lowpass_cutoff / 6.0 * delta_t));
                if (delta_t != 0.0)
                    w *= sin(2.0 * PI * lowpass_cutoff * delta_t) / (PI * delta_t);
                else
                    w *= 2.0 * lowpass_cutoff;
                w /= orig;
            }
            args.w[i][j] = (float)w;
        }
    }

    SpeedPerturb_resample_kernel<<<dim3(NBLK), dim3(BLK), 0, stream>>>(in, out, args);
}